// Round 1
// baseline (759.138 us; speedup 1.0000x reference)
//
#include <hip/hip_runtime.h>
#include <math.h>

#define TPB 256

constexpr int Dd = 256;
constexpr int Nn = 1024;
constexpr int Mm = 1025;      // Nn + 1 (with dustbin)
constexpr int LDKc = 1040;    // padded row stride for K / KT
constexpr int SINK_ITERS = 100;

// ---- workspace layout (float offsets) ----
constexpr size_t OF_MD0   = 0;
constexpr size_t OF_MD1   = OF_MD0  + (size_t)Dd*Nn;
constexpr size_t OF_MD0T  = OF_MD1  + (size_t)Dd*Nn;
constexpr size_t OF_MD1T  = OF_MD0T + (size_t)Dd*Nn;
constexpr size_t OF_HA    = OF_MD1T + (size_t)Dd*Nn;
constexpr size_t OF_HBT   = OF_HA   + (size_t)Nn*64;
constexpr size_t OF_ZFA   = OF_HBT  + (size_t)Nn*64;
constexpr size_t OF_ZFB   = OF_ZFA  + (size_t)Nn*Dd;
constexpr size_t OF_WZ1T  = OF_ZFB  + (size_t)Nn*Dd;
constexpr size_t OF_WZ2T  = OF_WZ1T + (size_t)Dd*Dd;
constexpr size_t OF_ZA    = OF_WZ2T + (size_t)64*Dd;
constexpr size_t OF_ZB    = OF_ZA   + Nn;
constexpr size_t OF_ROWM  = OF_ZB   + Nn;
constexpr size_t OF_ROWS  = OF_ROWM + Nn;
constexpr size_t OF_CMP   = OF_ROWS + Nn;        // 16 x 1024 column partial max
constexpr size_t OF_CSP   = OF_CMP  + (size_t)16*Nn;
constexpr size_t OF_COLM  = OF_CSP  + (size_t)16*Nn;
constexpr size_t OF_COLS  = OF_COLM + Nn;
constexpr size_t OF_AMP   = OF_COLS + Nn;        // col-argmax partial max
constexpr size_t OF_AIP   = OF_AMP  + (size_t)16*Nn;  // col-argmax partial idx (int)
constexpr size_t OF_AV    = OF_AIP  + (size_t)16*Nn;  // a vector (exp(u))
constexpr size_t OF_BV    = OF_AV   + LDKc;           // b vector (exp(v))
constexpr size_t OF_RV    = OF_BV   + LDKc;           // row sums
constexpr size_t OF_IDX0  = OF_RV   + LDKc;           // int
constexpr size_t OF_MAX0  = OF_IDX0 + Nn;
constexpr size_t OF_IDX1  = OF_MAX0 + Nn;             // int
constexpr size_t OF_ATTN  = OF_IDX1 + Nn;
constexpr size_t OF_PROBA = OF_ATTN + (size_t)Nn*Nn;
constexpr size_t OF_PROBB = OF_PROBA+ (size_t)Nn*Nn;
// K/KT alias the attn/probA/probB region (those are dead before K is built)
constexpr size_t OF_K     = OF_ATTN;
constexpr size_t OF_KT    = OF_K + (size_t)Mm*LDKc;

// mdesc = Wp @ desc + bp ; also writes transpose. grid (4, 64)
__global__ __launch_bounds__(TPB) void k_mdesc(const float* __restrict__ Wp,
                                               const float* __restrict__ bp,
                                               const float* __restrict__ desc,
                                               float* __restrict__ md,
                                               float* __restrict__ mdT) {
  int j = blockIdx.x * TPB + threadIdx.x;
  int d0 = blockIdx.y * 4;
  float acc[4] = {0.f, 0.f, 0.f, 0.f};
  for (int k = 0; k < Dd; ++k) {
    float v = desc[(size_t)k * Nn + j];
#pragma unroll
    for (int r = 0; r < 4; ++r) acc[r] += Wp[(size_t)(d0 + r) * Dd + k] * v;
  }
#pragma unroll
  for (int r = 0; r < 4; ++r) {
    acc[r] += bp[d0 + r];
    md[(size_t)(d0 + r) * Nn + j] = acc[r];
  }
  *(float4*)&mdT[(size_t)j * Dd + d0] = make_float4(acc[0], acc[1], acc[2], acc[3]);
}

// hA[n,o] = sum_d md0[d,n] W1[o,d]; hBt[o,n] = sum_d md1[d,n] W1[o,256+d]. grid (4,64,2)
__global__ __launch_bounds__(TPB) void k_h(const float* __restrict__ W1,
                                           const float* __restrict__ md0,
                                           const float* __restrict__ md1,
                                           float* __restrict__ hA,
                                           float* __restrict__ hBt) {
  int j = blockIdx.x * TPB + threadIdx.x;
  int o = blockIdx.y;
  int which = blockIdx.z;
  const float* md = which ? md1 : md0;
  const float* w = W1 + (size_t)o * 512 + which * 256;
  float acc = 0.f;
  for (int d = 0; d < Dd; ++d) acc += md[(size_t)d * Nn + j] * w[d];
  if (which == 0) hA[(size_t)j * 64 + o] = acc;
  else            hBt[(size_t)o * Nn + j] = acc;
}

// attn[i,j] = b2 + sum_o W2[o]*relu(hA[i,o]+hBt[o,j]+b1[o]). grid (4,256)
__global__ __launch_bounds__(TPB) void k_attn(const float* __restrict__ hA,
                                              const float* __restrict__ hBt,
                                              const float* __restrict__ W2,
                                              const float* __restrict__ b1,
                                              const float* __restrict__ b2,
                                              float* __restrict__ attn) {
  int j = blockIdx.x * TPB + threadIdx.x;
  int i0 = blockIdx.y * 4;
  float bias = b2[0];
  float acc[4] = {bias, bias, bias, bias};
  for (int o = 0; o < 64; ++o) {
    float hb = hBt[(size_t)o * Nn + j] + b1[o];
    float w = W2[o];
#pragma unroll
    for (int r = 0; r < 4; ++r) {
      float t = hA[(size_t)(i0 + r) * 64 + o] + hb;
      acc[r] += w * fmaxf(t, 0.f);
    }
  }
#pragma unroll
  for (int r = 0; r < 4; ++r) attn[(size_t)(i0 + r) * Nn + j] = acc[r];
}

// per-row softmax stats. grid 1024
__global__ __launch_bounds__(TPB) void k_rowstats(const float* __restrict__ attn,
                                                  float* __restrict__ rowM,
                                                  float* __restrict__ rowS) {
  int i = blockIdx.x, t = threadIdx.x;
  const float* row = attn + (size_t)i * Nn;
  float m = -INFINITY;
  for (int q = 0; q < 4; ++q) m = fmaxf(m, row[t + q * TPB]);
  __shared__ float red[TPB];
  red[t] = m; __syncthreads();
  for (int s = TPB / 2; s > 0; s >>= 1) {
    if (t < s) red[t] = fmaxf(red[t], red[t + s]);
    __syncthreads();
  }
  m = red[0]; __syncthreads();
  float ssum = 0.f;
  for (int q = 0; q < 4; ++q) ssum += expf(row[t + q * TPB] - m);
  red[t] = ssum; __syncthreads();
  for (int s = TPB / 2; s > 0; s >>= 1) {
    if (t < s) red[t] += red[t + s];
    __syncthreads();
  }
  if (t == 0) { rowM[i] = m; rowS[i] = red[0]; }
}

// column softmax stats, chunked over i. grid (4,16) then combine grid 4
__global__ __launch_bounds__(TPB) void k_colpart(const float* __restrict__ attn,
                                                 float* __restrict__ cmp,
                                                 float* __restrict__ csp) {
  int j = blockIdx.x * TPB + threadIdx.x;
  int c = blockIdx.y, i0 = c * 64;
  float m = -INFINITY;
  for (int q = 0; q < 64; ++q) m = fmaxf(m, attn[(size_t)(i0 + q) * Nn + j]);
  float s = 0.f;
  for (int q = 0; q < 64; ++q) s += expf(attn[(size_t)(i0 + q) * Nn + j] - m);
  cmp[(size_t)c * Nn + j] = m;
  csp[(size_t)c * Nn + j] = s;
}

__global__ __launch_bounds__(TPB) void k_colcomb(const float* __restrict__ cmp,
                                                 const float* __restrict__ csp,
                                                 float* __restrict__ colM,
                                                 float* __restrict__ colS) {
  int j = blockIdx.x * TPB + threadIdx.x;
  float m = -INFINITY;
  for (int c = 0; c < 16; ++c) m = fmaxf(m, cmp[(size_t)c * Nn + j]);
  float s = 0.f;
  for (int c = 0; c < 16; ++c) s += csp[(size_t)c * Nn + j] * expf(cmp[(size_t)c * Nn + j] - m);
  colM[j] = m; colS[j] = s;
}

// probA/probB materialization. grid (4,1024)
__global__ __launch_bounds__(TPB) void k_prob(const float* __restrict__ attn,
                                              const float* __restrict__ rowM,
                                              const float* __restrict__ rowS,
                                              const float* __restrict__ colM,
                                              const float* __restrict__ colS,
                                              float* __restrict__ probA,
                                              float* __restrict__ probB) {
  int j = blockIdx.x * TPB + threadIdx.x;
  int i = blockIdx.y;
  float v = attn[(size_t)i * Nn + j];
  probA[(size_t)i * Nn + j] = expf(v - rowM[i]) / rowS[i];
  probB[(size_t)i * Nn + j] = expf(v - colM[j]) / colS[j];
}

// zfeatA[i,d] = sum_j probA[i,j]*md1T[j,d]; zfeatB[j,d] = sum_i probB[i,j]*md0T[i,d]. grid (256,2)
__global__ __launch_bounds__(TPB) void k_zfeat(const float* __restrict__ probA,
                                               const float* __restrict__ probB,
                                               const float* __restrict__ md0T,
                                               const float* __restrict__ md1T,
                                               float* __restrict__ zfA,
                                               float* __restrict__ zfB) {
  int d = threadIdx.x;
  int r0 = blockIdx.x * 4;
  int which = blockIdx.y;
  float acc[4] = {0.f, 0.f, 0.f, 0.f};
  if (which == 0) {
    for (int j = 0; j < Nn; ++j) {
      float mv = md1T[(size_t)j * Dd + d];
#pragma unroll
      for (int r = 0; r < 4; ++r) acc[r] += probA[(size_t)(r0 + r) * Nn + j] * mv;
    }
#pragma unroll
    for (int r = 0; r < 4; ++r) zfA[(size_t)(r0 + r) * Dd + d] = acc[r];
  } else {
    for (int i = 0; i < Nn; ++i) {
      float mv = md0T[(size_t)i * Dd + d];
#pragma unroll
      for (int r = 0; r < 4; ++r) acc[r] += probB[(size_t)i * Nn + (r0 + r)] * mv;
    }
#pragma unroll
    for (int r = 0; r < 4; ++r) zfB[(size_t)(r0 + r) * Dd + d] = acc[r];
  }
}

// transpose Wz1 (256x256) and Wz2 (64x256). grid 320
__global__ __launch_bounds__(TPB) void k_transposeW(const float* __restrict__ Wz1,
                                                    const float* __restrict__ Wz2,
                                                    float* __restrict__ Wz1T,
                                                    float* __restrict__ Wz2T) {
  int t = threadIdx.x, b = blockIdx.x;
  if (b < 256) Wz1T[(size_t)t * 256 + b] = Wz1[(size_t)b * 256 + t];
  else {
    int o = b - 256;
    Wz2T[(size_t)t * 64 + o] = Wz2[(size_t)o * 256 + t];
  }
}

// zmlp over rows of zfeatA / zfeatB. grid (1024,2)
__global__ __launch_bounds__(TPB) void k_zmlp(const float* __restrict__ zfA,
                                              const float* __restrict__ zfB,
                                              const float* __restrict__ Wz1T,
                                              const float* __restrict__ bz1,
                                              const float* __restrict__ Wz2T,
                                              const float* __restrict__ bz2,
                                              const float* __restrict__ Wz3,
                                              const float* __restrict__ bz3,
                                              float* __restrict__ zA,
                                              float* __restrict__ zB) {
  int i = blockIdx.x, t = threadIdx.x, which = blockIdx.y;
  const float* x = (which ? zfB : zfA) + (size_t)i * Dd;
  __shared__ float xs[Dd];
  __shared__ float h1[Dd];
  __shared__ float h2[64];
  xs[t] = x[t];
  __syncthreads();
  float acc = bz1[t];
  for (int k = 0; k < Dd; ++k) acc += Wz1T[(size_t)k * Dd + t] * xs[k];
  h1[t] = fmaxf(acc, 0.f);
  __syncthreads();
  if (t < 64) {
    float a2 = bz2[t];
    for (int k = 0; k < Dd; ++k) a2 += Wz2T[(size_t)k * 64 + t] * h1[k];
    h2[t] = fmaxf(a2, 0.f);
  }
  __syncthreads();
  if (t < 64) {
    float p = Wz3[t] * h2[t];
#pragma unroll
    for (int off = 32; off > 0; off >>= 1) p += __shfl_down(p, off);
    if (t == 0) (which ? zB : zA)[i] = p + bz3[0];
  }
}

// K[i,j] = exp(scores[i,j]) for i,j<1024, also KT. grid (4,256)
__global__ __launch_bounds__(TPB) void k_buildK(const float* __restrict__ md0T,
                                                const float* __restrict__ md1,
                                                float* __restrict__ K,
                                                float* __restrict__ KT) {
  int j = blockIdx.x * TPB + threadIdx.x;
  int i0 = blockIdx.y * 4;
  float acc[4] = {0.f, 0.f, 0.f, 0.f};
  for (int d = 0; d < Dd; ++d) {
    float mv = md1[(size_t)d * Nn + j];
#pragma unroll
    for (int r = 0; r < 4; ++r) acc[r] += md0T[(size_t)(i0 + r) * Dd + d] * mv;
  }
  float vr[4];
#pragma unroll
  for (int r = 0; r < 4; ++r) {
    vr[r] = expf(acc[r] * 0.0625f);
    K[(size_t)(i0 + r) * LDKc + j] = vr[r];
  }
  *(float4*)&KT[(size_t)j * LDKc + i0] = make_float4(vr[0], vr[1], vr[2], vr[3]);
}

// dustbin row/col of K and KT. grid 5
__global__ __launch_bounds__(TPB) void k_edgeK(const float* __restrict__ zA,
                                               const float* __restrict__ zB,
                                               float* __restrict__ K,
                                               float* __restrict__ KT) {
  int idx = blockIdx.x * TPB + threadIdx.x;
  if (idx >= Mm) return;
  const float E1 = 2.7182818284590452f;  // exp(alpha=1)
  float ka = (idx < Nn) ? expf(zA[idx]) : E1;  // K[idx][1024]
  float kb = (idx < Nn) ? expf(zB[idx]) : E1;  // K[1024][idx]
  K[(size_t)idx * LDKc + Nn] = ka;
  KT[(size_t)Nn * LDKc + idx] = ka;
  K[(size_t)Nn * LDKc + idx] = kb;
  KT[(size_t)idx * LDKc + Nn] = kb;
}

__global__ __launch_bounds__(TPB) void k_sinkinit(float* __restrict__ bvec) {
  int idx = blockIdx.x * TPB + threadIdx.x;
  if (idx < Mm) bvec[idx] = 1.f;
}

// one Sinkhorn half-step: out = mu / (Kp @ in)  (or raw row-sums when raw!=0). grid 257
__global__ __launch_bounds__(TPB) void k_sinkrow(const float* __restrict__ Kp,
                                                 const float* __restrict__ in,
                                                 float* __restrict__ out,
                                                 int raw) {
  int w = threadIdx.x >> 6;
  int l = threadIdx.x & 63;
  int i = blockIdx.x * 4 + w;
  if (i >= Mm) return;
  const float* row = Kp + (size_t)i * LDKc;
  float acc = 0.f;
#pragma unroll
  for (int q = 0; q < 16; ++q) {
    int j = l + q * 64;
    acc += row[j] * in[j];
  }
  if (l == 0) acc += row[Nn] * in[Nn];
#pragma unroll
  for (int off = 32; off > 0; off >>= 1) acc += __shfl_down(acc, off);
  if (l == 0) {
    if (raw) out[i] = acc;
    else     out[i] = ((i < Nn) ? (1.0f / 2048.0f) : 0.5f) / acc;
  }
}

// S[i,j] = K[i,j]*b[j]/r[i]  (row softmax of Z in closed form). grid (5,1025)
__global__ __launch_bounds__(TPB) void k_S(const float* __restrict__ K,
                                           const float* __restrict__ bvec,
                                           const float* __restrict__ r,
                                           float* __restrict__ Sout) {
  int j = blockIdx.x * TPB + threadIdx.x;
  int i = blockIdx.y;
  if (j >= Mm) return;
  Sout[(size_t)i * Mm + j] = K[(size_t)i * LDKc + j] * bvec[j] / r[i];
}

// row argmax over inner part (j<1024). grid 1024
__global__ __launch_bounds__(TPB) void k_argmaxrow(const float* __restrict__ S,
                                                   int* __restrict__ idx0,
                                                   float* __restrict__ max0) {
  int i = blockIdx.x, t = threadIdx.x;
  const float* row = S + (size_t)i * Mm;
  float best = -INFINITY; int bj = 0;
  for (int q = 0; q < 4; ++q) {
    int j = t + q * TPB;
    float v = row[j];
    if (v > best) { best = v; bj = j; }
  }
  __shared__ float bv[TPB];
  __shared__ int bi[TPB];
  bv[t] = best; bi[t] = bj;
  __syncthreads();
  for (int s = TPB / 2; s > 0; s >>= 1) {
    if (t < s) {
      if (bv[t + s] > bv[t] || (bv[t + s] == bv[t] && bi[t + s] < bi[t])) {
        bv[t] = bv[t + s]; bi[t] = bi[t + s];
      }
    }
    __syncthreads();
  }
  if (t == 0) { idx0[i] = bi[0]; max0[i] = bv[0]; }
}

// column argmax, chunked. grid (4,16) then combine grid 4
__global__ __launch_bounds__(TPB) void k_argcolpart(const float* __restrict__ S,
                                                    float* __restrict__ amp,
                                                    int* __restrict__ aip) {
  int j = blockIdx.x * TPB + threadIdx.x;
  int c = blockIdx.y, i0 = c * 64;
  float best = -INFINITY; int bi = i0;
  for (int q = 0; q < 64; ++q) {
    float v = S[(size_t)(i0 + q) * Mm + j];
    if (v > best) { best = v; bi = i0 + q; }
  }
  amp[(size_t)c * Nn + j] = best;
  aip[(size_t)c * Nn + j] = bi;
}

__global__ __launch_bounds__(TPB) void k_argcolcomb(const float* __restrict__ amp,
                                                    const int* __restrict__ aip,
                                                    int* __restrict__ idx1) {
  int j = blockIdx.x * TPB + threadIdx.x;
  float best = -INFINITY; int bi = 0;
  for (int c = 0; c < 16; ++c) {
    float v = amp[(size_t)c * Nn + j];
    if (v > best) { best = v; bi = aip[(size_t)c * Nn + j]; }
  }
  idx1[j] = bi;
}

// mutual matching + outputs. 1 block x 1024 threads
__global__ __launch_bounds__(1024) void k_match(const int* __restrict__ idx0,
                                                const float* __restrict__ max0,
                                                const int* __restrict__ idx1,
                                                float* __restrict__ out) {
  int t = threadIdx.x;
  __shared__ float ms0[Nn];
  __shared__ int v0[Nn];
  __shared__ int i0s[Nn];
  int j0 = idx0[t];
  bool mut0 = (idx1[j0] == t);
  float m0 = mut0 ? expf(max0[t]) : 0.f;
  bool val0 = mut0 && (m0 > 0.2f);
  ms0[t] = m0; v0[t] = val0 ? 1 : 0; i0s[t] = j0;
  out[t] = val0 ? (float)j0 : -1.f;           // indices0
  out[2048 + t] = m0;                          // mscores0
  __syncthreads();
  int i1 = idx1[t];
  bool mut1 = (i0s[i1] == t);
  float m1 = mut1 ? ms0[i1] : 0.f;
  bool val1 = mut1 && (v0[i1] != 0);
  out[1024 + t] = val1 ? (float)i1 : -1.f;     // indices1
  out[3072 + t] = m1;                          // mscores1
}

extern "C" void kernel_launch(void* const* d_in, const int* in_sizes, int n_in,
                              void* d_out, int out_size, void* d_ws, size_t ws_size,
                              hipStream_t stream) {
  (void)in_sizes; (void)n_in; (void)out_size; (void)ws_size;
  const float* desc0 = (const float*)d_in[0];
  const float* desc1 = (const float*)d_in[1];
  const float* Wp    = (const float*)d_in[2];
  const float* bp    = (const float*)d_in[3];
  const float* W1    = (const float*)d_in[4];
  const float* b1    = (const float*)d_in[5];
  const float* W2    = (const float*)d_in[6];
  const float* b2    = (const float*)d_in[7];
  const float* Wz1   = (const float*)d_in[8];
  const float* bz1   = (const float*)d_in[9];
  const float* Wz2   = (const float*)d_in[10];
  const float* bz2   = (const float*)d_in[11];
  const float* Wz3   = (const float*)d_in[12];
  const float* bz3   = (const float*)d_in[13];
  float* ws  = (float*)d_ws;
  float* out = (float*)d_out;
  dim3 blk(TPB);

  k_mdesc<<<dim3(4, 64), blk, 0, stream>>>(Wp, bp, desc0, ws + OF_MD0, ws + OF_MD0T);
  k_mdesc<<<dim3(4, 64), blk, 0, stream>>>(Wp, bp, desc1, ws + OF_MD1, ws + OF_MD1T);
  k_h<<<dim3(4, 64, 2), blk, 0, stream>>>(W1, ws + OF_MD0, ws + OF_MD1, ws + OF_HA, ws + OF_HBT);
  k_attn<<<dim3(4, 256), blk, 0, stream>>>(ws + OF_HA, ws + OF_HBT, W2, b1, b2, ws + OF_ATTN);
  k_rowstats<<<dim3(1024), blk, 0, stream>>>(ws + OF_ATTN, ws + OF_ROWM, ws + OF_ROWS);
  k_colpart<<<dim3(4, 16), blk, 0, stream>>>(ws + OF_ATTN, ws + OF_CMP, ws + OF_CSP);
  k_colcomb<<<dim3(4), blk, 0, stream>>>(ws + OF_CMP, ws + OF_CSP, ws + OF_COLM, ws + OF_COLS);
  k_prob<<<dim3(4, 1024), blk, 0, stream>>>(ws + OF_ATTN, ws + OF_ROWM, ws + OF_ROWS,
                                            ws + OF_COLM, ws + OF_COLS,
                                            ws + OF_PROBA, ws + OF_PROBB);
  k_zfeat<<<dim3(256, 2), blk, 0, stream>>>(ws + OF_PROBA, ws + OF_PROBB,
                                            ws + OF_MD0T, ws + OF_MD1T,
                                            ws + OF_ZFA, ws + OF_ZFB);
  k_transposeW<<<dim3(320), blk, 0, stream>>>(Wz1, Wz2, ws + OF_WZ1T, ws + OF_WZ2T);
  k_zmlp<<<dim3(1024, 2), blk, 0, stream>>>(ws + OF_ZFA, ws + OF_ZFB,
                                            ws + OF_WZ1T, bz1, ws + OF_WZ2T, bz2,
                                            Wz3, bz3, ws + OF_ZA, ws + OF_ZB);
  // ---- K build (clobbers attn/probA/probB region) ----
  k_buildK<<<dim3(4, 256), blk, 0, stream>>>(ws + OF_MD0T, ws + OF_MD1,
                                             ws + OF_K, ws + OF_KT);
  k_edgeK<<<dim3(5), blk, 0, stream>>>(ws + OF_ZA, ws + OF_ZB, ws + OF_K, ws + OF_KT);
  // ---- linear-domain Sinkhorn ----
  float* Kp  = ws + OF_K;
  float* KTp = ws + OF_KT;
  float* av  = ws + OF_AV;
  float* bvv = ws + OF_BV;
  float* rv  = ws + OF_RV;
  k_sinkinit<<<dim3(5), blk, 0, stream>>>(bvv);
  for (int it = 0; it < SINK_ITERS; ++it) {
    k_sinkrow<<<dim3(257), blk, 0, stream>>>(Kp, bvv, av, 0);
    k_sinkrow<<<dim3(257), blk, 0, stream>>>(KTp, av, bvv, 0);
  }
  k_sinkrow<<<dim3(257), blk, 0, stream>>>(Kp, bvv, rv, 1);
  // ---- outputs ----
  float* Sout = out + 4096;
  k_S<<<dim3(5, 1025), blk, 0, stream>>>(Kp, bvv, rv, Sout);
  k_argmaxrow<<<dim3(1024), blk, 0, stream>>>(Sout, (int*)(ws + OF_IDX0), ws + OF_MAX0);
  k_argcolpart<<<dim3(4, 16), blk, 0, stream>>>(Sout, ws + OF_AMP, (int*)(ws + OF_AIP));
  k_argcolcomb<<<dim3(4), blk, 0, stream>>>(ws + OF_AMP, (const int*)(ws + OF_AIP),
                                            (int*)(ws + OF_IDX1));
  k_match<<<dim3(1), dim3(1024), 0, stream>>>((const int*)(ws + OF_IDX0), ws + OF_MAX0,
                                              (const int*)(ws + OF_IDX1), out);
}